// Round 2
// baseline (197.093 us; speedup 1.0000x reference)
//
#include <hip/hip_runtime.h>

// OrdinalWeightedError: out = sum((interp_pcnl(x_i) - pcnl[t_i])^2 * w[t_i]) / sum(w[t_i])
// C = 5 classes. Memory-bound streaming reduction over input(f32,N) + target(i32,N).
// Round 1: removed same-address fp64 atomics (block partials -> ws, final reduce kernel),
//          added 4-deep load ILP, dropped memset node.

#define OWE_THREADS 256
#define OWE_GRID 2048
#define OWE_C 5

__device__ __forceinline__ void owe_process(float xv, int tv,
                                            const float* __restrict__ s_pcnl,
                                            const float* __restrict__ s_w,
                                            float& acc_num, float& acc_den)
{
    float f = floorf(xv);

    // lookup(v): in-range (0 <= v <= C-1) -> pcnl[(int)v]; else v/(C-1) (= v*0.25f, exact)
    float pf, pc;
    {
        float v = f;
        int idx = (int)v;
        idx = idx < 0 ? 0 : (idx > OWE_C - 1 ? OWE_C - 1 : idx);
        bool inr = (v >= 0.0f) && (v <= (float)(OWE_C - 1));
        pf = inr ? s_pcnl[idx] : v * 0.25f;
    }
    {
        float v = f + 1.0f;
        int idx = (int)v;
        idx = idx < 0 ? 0 : (idx > OWE_C - 1 ? OWE_C - 1 : idx);
        bool inr = (v >= 0.0f) && (v <= (float)(OWE_C - 1));
        pc = inr ? s_pcnl[idx] : v * 0.25f;
    }

    float ip   = pf + (pc - pf) * (xv - f);
    float tp   = s_pcnl[tv];
    float w    = s_w[tv];
    float diff = ip - tp;
    acc_num = fmaf(diff * diff, w, acc_num);
    acc_den += w;
}

__global__ __launch_bounds__(OWE_THREADS, 8) void owe_reduce_kernel(
    const float* __restrict__ input,
    const int*   __restrict__ target,
    const float* __restrict__ weight,
    const float* __restrict__ dist,
    float2*      __restrict__ partials,
    int n4)
{
    __shared__ float s_pcnl[OWE_C];
    __shared__ float s_w[OWE_C];
    __shared__ float s_part[2][OWE_THREADS / 64];

    if (threadIdx.x == 0) {
        // pcnl[i] = (2*cs[i] - d[i] - d[0]) / (2*cs[C-1] - d[0] - d[C-1])
        float d0 = dist[0], d1 = dist[1], d2 = dist[2], d3 = dist[3], d4 = dist[4];
        float cs0 = d0;
        float cs1 = cs0 + d1;
        float cs2 = cs1 + d2;
        float cs3 = cs2 + d3;
        float cs4 = cs3 + d4;
        float inv = 1.0f / (2.0f * cs4 - d0 - d4);
        s_pcnl[0] = (2.0f * cs0 - d0 - d0) * inv;
        s_pcnl[1] = (2.0f * cs1 - d1 - d0) * inv;
        s_pcnl[2] = (2.0f * cs2 - d2 - d0) * inv;
        s_pcnl[3] = (2.0f * cs3 - d3 - d0) * inv;
        s_pcnl[4] = (2.0f * cs4 - d4 - d0) * inv;
        s_w[0] = weight[0]; s_w[1] = weight[1]; s_w[2] = weight[2];
        s_w[3] = weight[3]; s_w[4] = weight[4];
    }
    __syncthreads();

    float acc_num = 0.0f;
    float acc_den = 0.0f;

    const float4* __restrict__ in4 = (const float4*)input;
    const int4*   __restrict__ tg4 = (const int4*)target;

    int tid    = blockIdx.x * OWE_THREADS + threadIdx.x;
    int stride = gridDim.x * OWE_THREADS;

    int i = tid;
    // main loop: 4 float4+int4 pairs in flight (4-deep ILP, 32 data VGPRs)
    for (; i + 3 * stride < n4; i += 4 * stride) {
        float4 x[4];
        int4   t[4];
        #pragma unroll
        for (int u = 0; u < 4; ++u) x[u] = in4[i + u * stride];
        #pragma unroll
        for (int u = 0; u < 4; ++u) t[u] = tg4[i + u * stride];
        #pragma unroll
        for (int u = 0; u < 4; ++u) {
            owe_process(x[u].x, t[u].x, s_pcnl, s_w, acc_num, acc_den);
            owe_process(x[u].y, t[u].y, s_pcnl, s_w, acc_num, acc_den);
            owe_process(x[u].z, t[u].z, s_pcnl, s_w, acc_num, acc_den);
            owe_process(x[u].w, t[u].w, s_pcnl, s_w, acc_num, acc_den);
        }
    }
    // tail
    for (; i < n4; i += stride) {
        float4 x = in4[i];
        int4   t = tg4[i];
        owe_process(x.x, t.x, s_pcnl, s_w, acc_num, acc_den);
        owe_process(x.y, t.y, s_pcnl, s_w, acc_num, acc_den);
        owe_process(x.z, t.z, s_pcnl, s_w, acc_num, acc_den);
        owe_process(x.w, t.w, s_pcnl, s_w, acc_num, acc_den);
    }

    // wave64 reduction
    #pragma unroll
    for (int off = 32; off > 0; off >>= 1) {
        acc_num += __shfl_down(acc_num, off);
        acc_den += __shfl_down(acc_den, off);
    }
    int lane = threadIdx.x & 63;
    int wid  = threadIdx.x >> 6;
    if (lane == 0) {
        s_part[0][wid] = acc_num;
        s_part[1][wid] = acc_den;
    }
    __syncthreads();
    if (threadIdx.x == 0) {
        float n = 0.0f, d = 0.0f;
        #pragma unroll
        for (int w = 0; w < OWE_THREADS / 64; ++w) {
            n += s_part[0][w];
            d += s_part[1][w];
        }
        partials[blockIdx.x] = make_float2(n, d);  // contention-free store
    }
}

__global__ __launch_bounds__(256) void owe_final_kernel(
    const float2* __restrict__ partials, int nparts, float* __restrict__ out)
{
    __shared__ double s_n[4], s_d[4];
    double n = 0.0, d = 0.0;
    for (int i = threadIdx.x; i < nparts; i += 256) {
        float2 p = partials[i];
        n += (double)p.x;
        d += (double)p.y;
    }
    #pragma unroll
    for (int off = 32; off > 0; off >>= 1) {
        n += __shfl_down(n, off);
        d += __shfl_down(d, off);
    }
    int lane = threadIdx.x & 63;
    int wid  = threadIdx.x >> 6;
    if (lane == 0) { s_n[wid] = n; s_d[wid] = d; }
    __syncthreads();
    if (threadIdx.x == 0) {
        double nn = 0.0, dd = 0.0;
        #pragma unroll
        for (int w = 0; w < 4; ++w) { nn += s_n[w]; dd += s_d[w]; }
        out[0] = (float)(nn / dd);
    }
}

extern "C" void kernel_launch(void* const* d_in, const int* in_sizes, int n_in,
                              void* d_out, int out_size, void* d_ws, size_t ws_size,
                              hipStream_t stream) {
    const float* input  = (const float*)d_in[0];
    const int*   target = (const int*)  d_in[1];
    const float* weight = (const float*)d_in[2];
    const float* dist   = (const float*)d_in[3];
    float*  out      = (float*)d_out;
    float2* partials = (float2*)d_ws;

    int n  = in_sizes[0];
    int n4 = n / 4;  // N = 16,777,216 divisible by 4

    owe_reduce_kernel<<<OWE_GRID, OWE_THREADS, 0, stream>>>(input, target, weight, dist, partials, n4);
    owe_final_kernel<<<1, 256, 0, stream>>>(partials, OWE_GRID, out);
}

// Round 3
// 191.436 us; speedup vs baseline: 1.0295x; 1.0295x over previous
//
#include <hip/hip_runtime.h>

// OrdinalWeightedError: out = sum((interp_pcnl(x_i) - pcnl[t_i])^2 * w[t_i]) / sum(w[t_i])
// C = 5. Memory-bound streaming reduction over input(f32,N) + target(i32,N) = 128 MiB.
// Round 2: one-shot kernel (no grid-stride loop). 8 loads/thread issued up-front with
// NAMED variables (r1's x[4]/t[4] arrays were demoted to scratch: WRITE_SIZE 150 MB of
// spill traffic, VGPR_Count 32). 100% occupancy target.

#define OWE_T 256
#define OWE_J 4   // float4 chunks per thread -> 16 elements/thread
#define OWE_C 5

__device__ __forceinline__ void owe_process(float xv, int tv,
                                            const float2* __restrict__ s_tab,
                                            float& acc_num, float& acc_den)
{
    float f  = floorf(xv);
    float fr = xv - f;

    float v0 = f;
    float v1 = f + 1.0f;
    int   i0 = (int)v0;
    int   i1 = (int)v1;
    int   c0 = min(max(i0, 0), OWE_C - 1);   // v_med3
    int   c1 = min(max(i1, 0), OWE_C - 1);
    bool  r0 = (v0 >= 0.0f) && (v0 <= (float)(OWE_C - 1));
    bool  r1 = (v1 >= 0.0f) && (v1 <= (float)(OWE_C - 1));

    float pf = r0 ? s_tab[c0].x : v0 * 0.25f;   // x/(C-1) == x*0.25 exactly
    float pc = r1 ? s_tab[c1].x : v1 * 0.25f;

    float  ip = fmaf(pc - pf, fr, pf);
    float2 tw = s_tab[tv];                      // one ds_read_b64: {pcnl[t], w[t]}
    float  diff = ip - tw.x;
    acc_num = fmaf(diff * diff, tw.y, acc_num);
    acc_den += tw.y;
}

__global__ __launch_bounds__(OWE_T, 8) void owe_reduce_kernel(
    const float4* __restrict__ in4,
    const int4*   __restrict__ tg4,
    const float*  __restrict__ weight,
    const float*  __restrict__ dist,
    float2*       __restrict__ partials,
    int n4)
{
    __shared__ float2 s_tab[8];
    __shared__ float2 s_part[OWE_T / 64];

    if (threadIdx.x == 0) {
        // pcnl[i] = (2*cs[i] - d[i] - d[0]) / (2*cs[C-1] - d[0] - d[C-1])
        float d0 = dist[0], d1 = dist[1], d2 = dist[2], d3 = dist[3], d4 = dist[4];
        float cs1 = d0 + d1, cs2 = cs1 + d2, cs3 = cs2 + d3, cs4 = cs3 + d4;
        float inv = 1.0f / (2.0f * cs4 - d0 - d4);
        s_tab[0] = make_float2((2.0f * d0  - d0 - d0) * inv, weight[0]);
        s_tab[1] = make_float2((2.0f * cs1 - d1 - d0) * inv, weight[1]);
        s_tab[2] = make_float2((2.0f * cs2 - d2 - d0) * inv, weight[2]);
        s_tab[3] = make_float2((2.0f * cs3 - d3 - d0) * inv, weight[3]);
        s_tab[4] = make_float2((2.0f * cs4 - d4 - d0) * inv, weight[4]);
    }
    __syncthreads();

    float acc_num = 0.0f, acc_den = 0.0f;

    const int base = blockIdx.x * (OWE_T * OWE_J) + threadIdx.x;

    if ((blockIdx.x + 1) * (OWE_T * OWE_J) <= n4) {
        // fast path: straight-line, all 8 loads in flight, named regs only
        float4 x0 = in4[base + 0 * OWE_T];
        int4   t0 = tg4[base + 0 * OWE_T];
        float4 x1 = in4[base + 1 * OWE_T];
        int4   t1 = tg4[base + 1 * OWE_T];
        float4 x2 = in4[base + 2 * OWE_T];
        int4   t2 = tg4[base + 2 * OWE_T];
        float4 x3 = in4[base + 3 * OWE_T];
        int4   t3 = tg4[base + 3 * OWE_T];

        owe_process(x0.x, t0.x, s_tab, acc_num, acc_den);
        owe_process(x0.y, t0.y, s_tab, acc_num, acc_den);
        owe_process(x0.z, t0.z, s_tab, acc_num, acc_den);
        owe_process(x0.w, t0.w, s_tab, acc_num, acc_den);
        owe_process(x1.x, t1.x, s_tab, acc_num, acc_den);
        owe_process(x1.y, t1.y, s_tab, acc_num, acc_den);
        owe_process(x1.z, t1.z, s_tab, acc_num, acc_den);
        owe_process(x1.w, t1.w, s_tab, acc_num, acc_den);
        owe_process(x2.x, t2.x, s_tab, acc_num, acc_den);
        owe_process(x2.y, t2.y, s_tab, acc_num, acc_den);
        owe_process(x2.z, t2.z, s_tab, acc_num, acc_den);
        owe_process(x2.w, t2.w, s_tab, acc_num, acc_den);
        owe_process(x3.x, t3.x, s_tab, acc_num, acc_den);
        owe_process(x3.y, t3.y, s_tab, acc_num, acc_den);
        owe_process(x3.z, t3.z, s_tab, acc_num, acc_den);
        owe_process(x3.w, t3.w, s_tab, acc_num, acc_den);
    } else {
        // tail block (only when n4 % (T*J) != 0)
        for (int j = 0; j < OWE_J; ++j) {
            int idx = base + j * OWE_T;
            if (idx < n4) {
                float4 x = in4[idx];
                int4   t = tg4[idx];
                owe_process(x.x, t.x, s_tab, acc_num, acc_den);
                owe_process(x.y, t.y, s_tab, acc_num, acc_den);
                owe_process(x.z, t.z, s_tab, acc_num, acc_den);
                owe_process(x.w, t.w, s_tab, acc_num, acc_den);
            }
        }
    }

    // wave64 reduction
    #pragma unroll
    for (int off = 32; off > 0; off >>= 1) {
        acc_num += __shfl_down(acc_num, off);
        acc_den += __shfl_down(acc_den, off);
    }
    int lane = threadIdx.x & 63;
    int wid  = threadIdx.x >> 6;
    if (lane == 0) s_part[wid] = make_float2(acc_num, acc_den);
    __syncthreads();
    if (threadIdx.x == 0) {
        float n = 0.0f, d = 0.0f;
        #pragma unroll
        for (int w = 0; w < OWE_T / 64; ++w) { n += s_part[w].x; d += s_part[w].y; }
        partials[blockIdx.x] = make_float2(n, d);
    }
}

__global__ __launch_bounds__(256) void owe_final_kernel(
    const float2* __restrict__ partials, int nparts,
    const float*  __restrict__ input, const int* __restrict__ target,
    const float*  __restrict__ weight, const float* __restrict__ dist,
    int n, float* __restrict__ out)
{
    __shared__ double s_n[4], s_d[4];
    double nn = 0.0, dd = 0.0;
    for (int i = threadIdx.x; i < nparts; i += 256) {
        float2 p = partials[i];
        nn += (double)p.x;
        dd += (double)p.y;
    }
    #pragma unroll
    for (int off = 32; off > 0; off >>= 1) {
        nn += __shfl_down(nn, off);
        dd += __shfl_down(dd, off);
    }
    int lane = threadIdx.x & 63;
    int wid  = threadIdx.x >> 6;
    if (lane == 0) { s_n[wid] = nn; s_d[wid] = dd; }
    __syncthreads();
    if (threadIdx.x == 0) {
        double N = 0.0, D = 0.0;
        #pragma unroll
        for (int w = 0; w < 4; ++w) { N += s_n[w]; D += s_d[w]; }
        // leftover elements (n % 4 != 0) — none for N=2^24, kept for generality
        int rem_start = (n / 4) * 4;
        if (rem_start < n) {
            float d0 = dist[0], d1 = dist[1], d2 = dist[2], d3 = dist[3], d4 = dist[4];
            float cs1 = d0 + d1, cs2 = cs1 + d2, cs3 = cs2 + d3, cs4 = cs3 + d4;
            float inv = 1.0f / (2.0f * cs4 - d0 - d4);
            float pcnl[5] = {(2.0f * d0  - d0 - d0) * inv, (2.0f * cs1 - d1 - d0) * inv,
                             (2.0f * cs2 - d2 - d0) * inv, (2.0f * cs3 - d3 - d0) * inv,
                             (2.0f * cs4 - d4 - d0) * inv};
            for (int i = rem_start; i < n; ++i) {
                float xv = input[i];
                int   tv = target[i];
                float f  = floorf(xv);
                float v0 = f, v1 = f + 1.0f;
                int c0 = min(max((int)v0, 0), 4), c1 = min(max((int)v1, 0), 4);
                float pf = (v0 >= 0.0f && v0 <= 4.0f) ? pcnl[c0] : v0 * 0.25f;
                float pc = (v1 >= 0.0f && v1 <= 4.0f) ? pcnl[c1] : v1 * 0.25f;
                float ip = pf + (pc - pf) * (xv - f);
                float diff = ip - pcnl[tv];
                float w = weight[tv];
                N += (double)(diff * diff * w);
                D += (double)w;
            }
        }
        out[0] = (float)(N / D);
    }
}

extern "C" void kernel_launch(void* const* d_in, const int* in_sizes, int n_in,
                              void* d_out, int out_size, void* d_ws, size_t ws_size,
                              hipStream_t stream) {
    const float* input  = (const float*)d_in[0];
    const int*   target = (const int*)  d_in[1];
    const float* weight = (const float*)d_in[2];
    const float* dist   = (const float*)d_in[3];
    float*  out      = (float*)d_out;
    float2* partials = (float2*)d_ws;

    int n  = in_sizes[0];
    int n4 = n / 4;
    int grid = (n4 + OWE_T * OWE_J - 1) / (OWE_T * OWE_J);   // 4096 for N=2^24

    owe_reduce_kernel<<<grid, OWE_T, 0, stream>>>(
        (const float4*)input, (const int4*)target, weight, dist, partials, n4);
    owe_final_kernel<<<1, 256, 0, stream>>>(
        partials, grid, input, target, weight, dist, n, out);
}

// Round 4
// 151.987 us; speedup vs baseline: 1.2968x; 1.2596x over previous
//
#include <hip/hip_runtime.h>

// OrdinalWeightedError: out = sum((interp_pcnl(x_i) - pcnl[t_i])^2 * w[t_i]) / sum(w[t_i])
// C = 5. Memory-bound streaming reduction over input(f32,N) + target(i32,N) = 128 MiB.
// Round 3: removed __launch_bounds__ min-waves clamp. r1/r2 both had ",8" and both
// showed VGPR_Count=32 + ~135 MB WRITE_SIZE = all 8 in-flight load results spilled to
// scratch (128 B/thread x 1M threads = 134 MB). r0 without the clamp had no spills.

#define OWE_T 256
#define OWE_J 4   // float4 chunks per thread -> 16 elements/thread
#define OWE_C 5

__device__ __forceinline__ void owe_process(float xv, int tv,
                                            const float2* __restrict__ s_tab,
                                            float& acc_num, float& acc_den)
{
    float f  = floorf(xv);
    float fr = xv - f;

    float v0 = f;
    float v1 = f + 1.0f;
    int   i0 = (int)v0;
    int   i1 = (int)v1;
    int   c0 = min(max(i0, 0), OWE_C - 1);   // v_med3
    int   c1 = min(max(i1, 0), OWE_C - 1);
    bool  r0 = (v0 >= 0.0f) && (v0 <= (float)(OWE_C - 1));
    bool  r1 = (v1 >= 0.0f) && (v1 <= (float)(OWE_C - 1));

    float pf = r0 ? s_tab[c0].x : v0 * 0.25f;   // x/(C-1) == x*0.25 exactly
    float pc = r1 ? s_tab[c1].x : v1 * 0.25f;

    float  ip = fmaf(pc - pf, fr, pf);
    float2 tw = s_tab[tv];                      // one ds_read_b64: {pcnl[t], w[t]}
    float  diff = ip - tw.x;
    acc_num = fmaf(diff * diff, tw.y, acc_num);
    acc_den += tw.y;
}

__global__ __launch_bounds__(OWE_T) void owe_reduce_kernel(
    const float4* __restrict__ in4,
    const int4*   __restrict__ tg4,
    const float*  __restrict__ weight,
    const float*  __restrict__ dist,
    float2*       __restrict__ partials,
    int n4)
{
    __shared__ float2 s_tab[8];
    __shared__ float2 s_part[OWE_T / 64];

    if (threadIdx.x == 0) {
        // pcnl[i] = (2*cs[i] - d[i] - d[0]) / (2*cs[C-1] - d[0] - d[C-1])
        float d0 = dist[0], d1 = dist[1], d2 = dist[2], d3 = dist[3], d4 = dist[4];
        float cs1 = d0 + d1, cs2 = cs1 + d2, cs3 = cs2 + d3, cs4 = cs3 + d4;
        float inv = 1.0f / (2.0f * cs4 - d0 - d4);
        s_tab[0] = make_float2((2.0f * d0  - d0 - d0) * inv, weight[0]);
        s_tab[1] = make_float2((2.0f * cs1 - d1 - d0) * inv, weight[1]);
        s_tab[2] = make_float2((2.0f * cs2 - d2 - d0) * inv, weight[2]);
        s_tab[3] = make_float2((2.0f * cs3 - d3 - d0) * inv, weight[3]);
        s_tab[4] = make_float2((2.0f * cs4 - d4 - d0) * inv, weight[4]);
    }
    __syncthreads();

    float acc_num = 0.0f, acc_den = 0.0f;

    const int base = blockIdx.x * (OWE_T * OWE_J) + threadIdx.x;

    if ((blockIdx.x + 1) * (OWE_T * OWE_J) <= n4) {
        // fast path: straight-line, all 8 loads in flight, named regs only
        float4 x0 = in4[base + 0 * OWE_T];
        int4   t0 = tg4[base + 0 * OWE_T];
        float4 x1 = in4[base + 1 * OWE_T];
        int4   t1 = tg4[base + 1 * OWE_T];
        float4 x2 = in4[base + 2 * OWE_T];
        int4   t2 = tg4[base + 2 * OWE_T];
        float4 x3 = in4[base + 3 * OWE_T];
        int4   t3 = tg4[base + 3 * OWE_T];

        owe_process(x0.x, t0.x, s_tab, acc_num, acc_den);
        owe_process(x0.y, t0.y, s_tab, acc_num, acc_den);
        owe_process(x0.z, t0.z, s_tab, acc_num, acc_den);
        owe_process(x0.w, t0.w, s_tab, acc_num, acc_den);
        owe_process(x1.x, t1.x, s_tab, acc_num, acc_den);
        owe_process(x1.y, t1.y, s_tab, acc_num, acc_den);
        owe_process(x1.z, t1.z, s_tab, acc_num, acc_den);
        owe_process(x1.w, t1.w, s_tab, acc_num, acc_den);
        owe_process(x2.x, t2.x, s_tab, acc_num, acc_den);
        owe_process(x2.y, t2.y, s_tab, acc_num, acc_den);
        owe_process(x2.z, t2.z, s_tab, acc_num, acc_den);
        owe_process(x2.w, t2.w, s_tab, acc_num, acc_den);
        owe_process(x3.x, t3.x, s_tab, acc_num, acc_den);
        owe_process(x3.y, t3.y, s_tab, acc_num, acc_den);
        owe_process(x3.z, t3.z, s_tab, acc_num, acc_den);
        owe_process(x3.w, t3.w, s_tab, acc_num, acc_den);
    } else {
        // tail block (only when n4 % (T*J) != 0)
        for (int j = 0; j < OWE_J; ++j) {
            int idx = base + j * OWE_T;
            if (idx < n4) {
                float4 x = in4[idx];
                int4   t = tg4[idx];
                owe_process(x.x, t.x, s_tab, acc_num, acc_den);
                owe_process(x.y, t.y, s_tab, acc_num, acc_den);
                owe_process(x.z, t.z, s_tab, acc_num, acc_den);
                owe_process(x.w, t.w, s_tab, acc_num, acc_den);
            }
        }
    }

    // wave64 reduction
    #pragma unroll
    for (int off = 32; off > 0; off >>= 1) {
        acc_num += __shfl_down(acc_num, off);
        acc_den += __shfl_down(acc_den, off);
    }
    int lane = threadIdx.x & 63;
    int wid  = threadIdx.x >> 6;
    if (lane == 0) s_part[wid] = make_float2(acc_num, acc_den);
    __syncthreads();
    if (threadIdx.x == 0) {
        float n = 0.0f, d = 0.0f;
        #pragma unroll
        for (int w = 0; w < OWE_T / 64; ++w) { n += s_part[w].x; d += s_part[w].y; }
        partials[blockIdx.x] = make_float2(n, d);
    }
}

__global__ __launch_bounds__(256) void owe_final_kernel(
    const float2* __restrict__ partials, int nparts,
    const float*  __restrict__ input, const int* __restrict__ target,
    const float*  __restrict__ weight, const float* __restrict__ dist,
    int n, float* __restrict__ out)
{
    __shared__ double s_n[4], s_d[4];
    double nn = 0.0, dd = 0.0;
    for (int i = threadIdx.x; i < nparts; i += 256) {
        float2 p = partials[i];
        nn += (double)p.x;
        dd += (double)p.y;
    }
    #pragma unroll
    for (int off = 32; off > 0; off >>= 1) {
        nn += __shfl_down(nn, off);
        dd += __shfl_down(dd, off);
    }
    int lane = threadIdx.x & 63;
    int wid  = threadIdx.x >> 6;
    if (lane == 0) { s_n[wid] = nn; s_d[wid] = dd; }
    __syncthreads();
    if (threadIdx.x == 0) {
        double N = 0.0, D = 0.0;
        #pragma unroll
        for (int w = 0; w < 4; ++w) { N += s_n[w]; D += s_d[w]; }
        // leftover elements (n % 4 != 0) — none for N=2^24, kept for generality
        int rem_start = (n / 4) * 4;
        if (rem_start < n) {
            float d0 = dist[0], d1 = dist[1], d2 = dist[2], d3 = dist[3], d4 = dist[4];
            float cs1 = d0 + d1, cs2 = cs1 + d2, cs3 = cs2 + d3, cs4 = cs3 + d4;
            float inv = 1.0f / (2.0f * cs4 - d0 - d4);
            float pcnl[5] = {(2.0f * d0  - d0 - d0) * inv, (2.0f * cs1 - d1 - d0) * inv,
                             (2.0f * cs2 - d2 - d0) * inv, (2.0f * cs3 - d3 - d0) * inv,
                             (2.0f * cs4 - d4 - d0) * inv};
            for (int i = rem_start; i < n; ++i) {
                float xv = input[i];
                int   tv = target[i];
                float f  = floorf(xv);
                float v0 = f, v1 = f + 1.0f;
                int c0 = min(max((int)v0, 0), 4), c1 = min(max((int)v1, 0), 4);
                float pf = (v0 >= 0.0f && v0 <= 4.0f) ? pcnl[c0] : v0 * 0.25f;
                float pc = (v1 >= 0.0f && v1 <= 4.0f) ? pcnl[c1] : v1 * 0.25f;
                float ip = pf + (pc - pf) * (xv - f);
                float diff = ip - pcnl[tv];
                float w = weight[tv];
                N += (double)(diff * diff * w);
                D += (double)w;
            }
        }
        out[0] = (float)(N / D);
    }
}

extern "C" void kernel_launch(void* const* d_in, const int* in_sizes, int n_in,
                              void* d_out, int out_size, void* d_ws, size_t ws_size,
                              hipStream_t stream) {
    const float* input  = (const float*)d_in[0];
    const int*   target = (const int*)  d_in[1];
    const float* weight = (const float*)d_in[2];
    const float* dist   = (const float*)d_in[3];
    float*  out      = (float*)d_out;
    float2* partials = (float2*)d_ws;

    int n  = in_sizes[0];
    int n4 = n / 4;
    int grid = (n4 + OWE_T * OWE_J - 1) / (OWE_T * OWE_J);   // 4096 for N=2^24

    owe_reduce_kernel<<<grid, OWE_T, 0, stream>>>(
        (const float4*)input, (const int4*)target, weight, dist, partials, n4);
    owe_final_kernel<<<1, 256, 0, stream>>>(
        partials, grid, input, target, weight, dist, n, out);
}

// Round 6
// 149.375 us; speedup vs baseline: 1.3195x; 1.0175x over previous
//
#include <hip/hip_runtime.h>

// OrdinalWeightedError: out = sum((interp_pcnl(x_i) - pcnl[t_i])^2 * w[t_i]) / sum(w[t_i])
// C = 5. Memory-bound streaming reduction over input(f32,N) + target(i32,N) = 128 MiB.
// Round 4 (resubmit after GPU acquisition timeout): J=4 -> J=8 (16 loads in
// flight/wave, named scalars). Measured ladder: 2 in flight -> 1.7 TB/s (r0),
// 8 -> 3.2 TB/s (r3 result). Pushing the same lever.
// NO __launch_bounds__ min-waves arg (r1/r2: ",8" clamped VGPR to 32 and spilled all
// load results to scratch -> 135 MB WRITE_SIZE; r3 removed it: 52 VGPR, no spill).

#define OWE_T 256
#define OWE_J 8   // float4 chunks per thread -> 32 elements/thread
#define OWE_C 5

__device__ __forceinline__ void owe_process(float xv, int tv,
                                            const float2* __restrict__ s_tab,
                                            float& acc_num, float& acc_den)
{
    float f  = floorf(xv);
    float fr = xv - f;

    float v0 = f;
    float v1 = f + 1.0f;
    int   c0 = min(max((int)v0, 0), OWE_C - 1);   // v_med3
    int   c1 = min(max((int)v1, 0), OWE_C - 1);
    bool  r0 = (v0 >= 0.0f) && (v0 <= (float)(OWE_C - 1));
    bool  r1 = (v1 >= 0.0f) && (v1 <= (float)(OWE_C - 1));

    float pf = r0 ? s_tab[c0].x : v0 * 0.25f;   // x/(C-1) == x*0.25 exactly
    float pc = r1 ? s_tab[c1].x : v1 * 0.25f;

    float  ip = fmaf(pc - pf, fr, pf);
    float2 tw = s_tab[tv];                      // one ds_read_b64: {pcnl[t], w[t]}
    float  diff = ip - tw.x;
    acc_num = fmaf(diff * diff, tw.y, acc_num);
    acc_den += tw.y;
}

__global__ __launch_bounds__(OWE_T) void owe_reduce_kernel(
    const float4* __restrict__ in4,
    const int4*   __restrict__ tg4,
    const float*  __restrict__ weight,
    const float*  __restrict__ dist,
    float2*       __restrict__ partials,
    int n4)
{
    __shared__ float2 s_tab[8];
    __shared__ float2 s_part[OWE_T / 64];

    if (threadIdx.x == 0) {
        // pcnl[i] = (2*cs[i] - d[i] - d[0]) / (2*cs[C-1] - d[0] - d[C-1])
        float d0 = dist[0], d1 = dist[1], d2 = dist[2], d3 = dist[3], d4 = dist[4];
        float cs1 = d0 + d1, cs2 = cs1 + d2, cs3 = cs2 + d3, cs4 = cs3 + d4;
        float inv = 1.0f / (2.0f * cs4 - d0 - d4);
        s_tab[0] = make_float2((2.0f * d0  - d0 - d0) * inv, weight[0]);
        s_tab[1] = make_float2((2.0f * cs1 - d1 - d0) * inv, weight[1]);
        s_tab[2] = make_float2((2.0f * cs2 - d2 - d0) * inv, weight[2]);
        s_tab[3] = make_float2((2.0f * cs3 - d3 - d0) * inv, weight[3]);
        s_tab[4] = make_float2((2.0f * cs4 - d4 - d0) * inv, weight[4]);
    }
    __syncthreads();

    float acc_num = 0.0f, acc_den = 0.0f;

    const int base = blockIdx.x * (OWE_T * OWE_J) + threadIdx.x;

    if ((blockIdx.x + 1) * (OWE_T * OWE_J) <= n4) {
        // fast path: straight-line, 16 loads in flight, named regs only.
        // Consumption follows issue order -> compiler uses counted vmcnt waits,
        // overlapping early-batch compute with late-batch loads.
        float4 x0 = in4[base + 0 * OWE_T];
        int4   t0 = tg4[base + 0 * OWE_T];
        float4 x1 = in4[base + 1 * OWE_T];
        int4   t1 = tg4[base + 1 * OWE_T];
        float4 x2 = in4[base + 2 * OWE_T];
        int4   t2 = tg4[base + 2 * OWE_T];
        float4 x3 = in4[base + 3 * OWE_T];
        int4   t3 = tg4[base + 3 * OWE_T];
        float4 x4 = in4[base + 4 * OWE_T];
        int4   t4 = tg4[base + 4 * OWE_T];
        float4 x5 = in4[base + 5 * OWE_T];
        int4   t5 = tg4[base + 5 * OWE_T];
        float4 x6 = in4[base + 6 * OWE_T];
        int4   t6 = tg4[base + 6 * OWE_T];
        float4 x7 = in4[base + 7 * OWE_T];
        int4   t7 = tg4[base + 7 * OWE_T];

        owe_process(x0.x, t0.x, s_tab, acc_num, acc_den);
        owe_process(x0.y, t0.y, s_tab, acc_num, acc_den);
        owe_process(x0.z, t0.z, s_tab, acc_num, acc_den);
        owe_process(x0.w, t0.w, s_tab, acc_num, acc_den);
        owe_process(x1.x, t1.x, s_tab, acc_num, acc_den);
        owe_process(x1.y, t1.y, s_tab, acc_num, acc_den);
        owe_process(x1.z, t1.z, s_tab, acc_num, acc_den);
        owe_process(x1.w, t1.w, s_tab, acc_num, acc_den);
        owe_process(x2.x, t2.x, s_tab, acc_num, acc_den);
        owe_process(x2.y, t2.y, s_tab, acc_num, acc_den);
        owe_process(x2.z, t2.z, s_tab, acc_num, acc_den);
        owe_process(x2.w, t2.w, s_tab, acc_num, acc_den);
        owe_process(x3.x, t3.x, s_tab, acc_num, acc_den);
        owe_process(x3.y, t3.y, s_tab, acc_num, acc_den);
        owe_process(x3.z, t3.z, s_tab, acc_num, acc_den);
        owe_process(x3.w, t3.w, s_tab, acc_num, acc_den);
        owe_process(x4.x, t4.x, s_tab, acc_num, acc_den);
        owe_process(x4.y, t4.y, s_tab, acc_num, acc_den);
        owe_process(x4.z, t4.z, s_tab, acc_num, acc_den);
        owe_process(x4.w, t4.w, s_tab, acc_num, acc_den);
        owe_process(x5.x, t5.x, s_tab, acc_num, acc_den);
        owe_process(x5.y, t5.y, s_tab, acc_num, acc_den);
        owe_process(x5.z, t5.z, s_tab, acc_num, acc_den);
        owe_process(x5.w, t5.w, s_tab, acc_num, acc_den);
        owe_process(x6.x, t6.x, s_tab, acc_num, acc_den);
        owe_process(x6.y, t6.y, s_tab, acc_num, acc_den);
        owe_process(x6.z, t6.z, s_tab, acc_num, acc_den);
        owe_process(x6.w, t6.w, s_tab, acc_num, acc_den);
        owe_process(x7.x, t7.x, s_tab, acc_num, acc_den);
        owe_process(x7.y, t7.y, s_tab, acc_num, acc_den);
        owe_process(x7.z, t7.z, s_tab, acc_num, acc_den);
        owe_process(x7.w, t7.w, s_tab, acc_num, acc_den);
    } else {
        // tail block (only when n4 % (T*J) != 0)
        for (int j = 0; j < OWE_J; ++j) {
            int idx = base + j * OWE_T;
            if (idx < n4) {
                float4 x = in4[idx];
                int4   t = tg4[idx];
                owe_process(x.x, t.x, s_tab, acc_num, acc_den);
                owe_process(x.y, t.y, s_tab, acc_num, acc_den);
                owe_process(x.z, t.z, s_tab, acc_num, acc_den);
                owe_process(x.w, t.w, s_tab, acc_num, acc_den);
            }
        }
    }

    // wave64 reduction
    #pragma unroll
    for (int off = 32; off > 0; off >>= 1) {
        acc_num += __shfl_down(acc_num, off);
        acc_den += __shfl_down(acc_den, off);
    }
    int lane = threadIdx.x & 63;
    int wid  = threadIdx.x >> 6;
    if (lane == 0) s_part[wid] = make_float2(acc_num, acc_den);
    __syncthreads();
    if (threadIdx.x == 0) {
        float n = 0.0f, d = 0.0f;
        #pragma unroll
        for (int w = 0; w < OWE_T / 64; ++w) { n += s_part[w].x; d += s_part[w].y; }
        partials[blockIdx.x] = make_float2(n, d);
    }
}

__global__ __launch_bounds__(256) void owe_final_kernel(
    const float2* __restrict__ partials, int nparts,
    const float*  __restrict__ input, const int* __restrict__ target,
    const float*  __restrict__ weight, const float* __restrict__ dist,
    int n, float* __restrict__ out)
{
    __shared__ double s_n[4], s_d[4];
    double nn = 0.0, dd = 0.0;
    for (int i = threadIdx.x; i < nparts; i += 256) {
        float2 p = partials[i];
        nn += (double)p.x;
        dd += (double)p.y;
    }
    #pragma unroll
    for (int off = 32; off > 0; off >>= 1) {
        nn += __shfl_down(nn, off);
        dd += __shfl_down(dd, off);
    }
    int lane = threadIdx.x & 63;
    int wid  = threadIdx.x >> 6;
    if (lane == 0) { s_n[wid] = nn; s_d[wid] = dd; }
    __syncthreads();
    if (threadIdx.x == 0) {
        double N = 0.0, D = 0.0;
        #pragma unroll
        for (int w = 0; w < 4; ++w) { N += s_n[w]; D += s_d[w]; }
        // leftover elements (n % 4 != 0) — none for N=2^24, kept for generality
        int rem_start = (n / 4) * 4;
        if (rem_start < n) {
            float d0 = dist[0], d1 = dist[1], d2 = dist[2], d3 = dist[3], d4 = dist[4];
            float cs1 = d0 + d1, cs2 = cs1 + d2, cs3 = cs2 + d3, cs4 = cs3 + d4;
            float inv = 1.0f / (2.0f * cs4 - d0 - d4);
            float pcnl[5] = {(2.0f * d0  - d0 - d0) * inv, (2.0f * cs1 - d1 - d0) * inv,
                             (2.0f * cs2 - d2 - d0) * inv, (2.0f * cs3 - d3 - d0) * inv,
                             (2.0f * cs4 - d4 - d0) * inv};
            for (int i = rem_start; i < n; ++i) {
                float xv = input[i];
                int   tv = target[i];
                float f  = floorf(xv);
                float v0 = f, v1 = f + 1.0f;
                int c0 = min(max((int)v0, 0), 4), c1 = min(max((int)v1, 0), 4);
                float pf = (v0 >= 0.0f && v0 <= 4.0f) ? pcnl[c0] : v0 * 0.25f;
                float pc = (v1 >= 0.0f && v1 <= 4.0f) ? pcnl[c1] : v1 * 0.25f;
                float ip = pf + (pc - pf) * (xv - f);
                float diff = ip - pcnl[tv];
                float w = weight[tv];
                N += (double)(diff * diff * w);
                D += (double)w;
            }
        }
        out[0] = (float)(N / D);
    }
}

extern "C" void kernel_launch(void* const* d_in, const int* in_sizes, int n_in,
                              void* d_out, int out_size, void* d_ws, size_t ws_size,
                              hipStream_t stream) {
    const float* input  = (const float*)d_in[0];
    const int*   target = (const int*)  d_in[1];
    const float* weight = (const float*)d_in[2];
    const float* dist   = (const float*)d_in[3];
    float*  out      = (float*)d_out;
    float2* partials = (float2*)d_ws;

    int n  = in_sizes[0];
    int n4 = n / 4;
    int grid = (n4 + OWE_T * OWE_J - 1) / (OWE_T * OWE_J);   // 2048 for N=2^24

    owe_reduce_kernel<<<grid, OWE_T, 0, stream>>>(
        (const float4*)input, (const int4*)target, weight, dist, partials, n4);
    owe_final_kernel<<<1, 256, 0, stream>>>(
        partials, grid, input, target, weight, dist, n, out);
}

// Round 7
// 143.668 us; speedup vs baseline: 1.3719x; 1.0397x over previous
//
#include <hip/hip_runtime.h>

// OrdinalWeightedError: out = sum((interp_pcnl(x_i) - pcnl[t_i])^2 * w[t_i]) / sum(w[t_i])
// C = 5. Memory-bound streaming reduction over input(f32,N) + target(i32,N) = 128 MiB.
// Round 7: r3/r6 flat at ~3.0-3.1 TB/s total traffic across 2x different ILP/occupancy
// shapes (in-flight bytes/CU constant ~75 KB) => service-rate ceiling suspect, not
// latency. Single change vs r3: non-temporal loads on both streams (read-once data;
// default policy thrashes the L3-resident restore copy). J=4, 4096 blocks, VGPR~52.
// NO __launch_bounds__ min-waves arg (r1/r2: ",8" clamped VGPR to 32 -> full spill).

#define OWE_T 256
#define OWE_J 4   // float4 chunks per thread -> 16 elements/thread
#define OWE_C 5

typedef float f32x4 __attribute__((ext_vector_type(4)));
typedef int   i32x4 __attribute__((ext_vector_type(4)));

__device__ __forceinline__ void owe_process(float xv, int tv,
                                            const float2* __restrict__ s_tab,
                                            float& acc_num, float& acc_den)
{
    float f  = floorf(xv);
    float fr = xv - f;

    float v0 = f;
    float v1 = f + 1.0f;
    int   c0 = min(max((int)v0, 0), OWE_C - 1);   // v_med3
    int   c1 = min(max((int)v1, 0), OWE_C - 1);
    bool  r0 = (v0 >= 0.0f) && (v0 <= (float)(OWE_C - 1));
    bool  r1 = (v1 >= 0.0f) && (v1 <= (float)(OWE_C - 1));

    float pf = r0 ? s_tab[c0].x : v0 * 0.25f;   // x/(C-1) == x*0.25 exactly
    float pc = r1 ? s_tab[c1].x : v1 * 0.25f;

    float  ip = fmaf(pc - pf, fr, pf);
    float2 tw = s_tab[tv];                      // one ds_read_b64: {pcnl[t], w[t]}
    float  diff = ip - tw.x;
    acc_num = fmaf(diff * diff, tw.y, acc_num);
    acc_den += tw.y;
}

__global__ __launch_bounds__(OWE_T) void owe_reduce_kernel(
    const f32x4* __restrict__ in4,
    const i32x4* __restrict__ tg4,
    const float* __restrict__ weight,
    const float* __restrict__ dist,
    float2*      __restrict__ partials,
    int n4)
{
    __shared__ float2 s_tab[8];
    __shared__ float2 s_part[OWE_T / 64];

    if (threadIdx.x == 0) {
        // pcnl[i] = (2*cs[i] - d[i] - d[0]) / (2*cs[C-1] - d[0] - d[C-1])
        float d0 = dist[0], d1 = dist[1], d2 = dist[2], d3 = dist[3], d4 = dist[4];
        float cs1 = d0 + d1, cs2 = cs1 + d2, cs3 = cs2 + d3, cs4 = cs3 + d4;
        float inv = 1.0f / (2.0f * cs4 - d0 - d4);
        s_tab[0] = make_float2((2.0f * d0  - d0 - d0) * inv, weight[0]);
        s_tab[1] = make_float2((2.0f * cs1 - d1 - d0) * inv, weight[1]);
        s_tab[2] = make_float2((2.0f * cs2 - d2 - d0) * inv, weight[2]);
        s_tab[3] = make_float2((2.0f * cs3 - d3 - d0) * inv, weight[3]);
        s_tab[4] = make_float2((2.0f * cs4 - d4 - d0) * inv, weight[4]);
    }
    __syncthreads();

    float acc_num = 0.0f, acc_den = 0.0f;

    const int base = blockIdx.x * (OWE_T * OWE_J) + threadIdx.x;

    if ((blockIdx.x + 1) * (OWE_T * OWE_J) <= n4) {
        // fast path: straight-line, 8 nt-loads in flight, named regs only
        f32x4 x0 = __builtin_nontemporal_load(&in4[base + 0 * OWE_T]);
        i32x4 t0 = __builtin_nontemporal_load(&tg4[base + 0 * OWE_T]);
        f32x4 x1 = __builtin_nontemporal_load(&in4[base + 1 * OWE_T]);
        i32x4 t1 = __builtin_nontemporal_load(&tg4[base + 1 * OWE_T]);
        f32x4 x2 = __builtin_nontemporal_load(&in4[base + 2 * OWE_T]);
        i32x4 t2 = __builtin_nontemporal_load(&tg4[base + 2 * OWE_T]);
        f32x4 x3 = __builtin_nontemporal_load(&in4[base + 3 * OWE_T]);
        i32x4 t3 = __builtin_nontemporal_load(&tg4[base + 3 * OWE_T]);

        owe_process(x0.x, t0.x, s_tab, acc_num, acc_den);
        owe_process(x0.y, t0.y, s_tab, acc_num, acc_den);
        owe_process(x0.z, t0.z, s_tab, acc_num, acc_den);
        owe_process(x0.w, t0.w, s_tab, acc_num, acc_den);
        owe_process(x1.x, t1.x, s_tab, acc_num, acc_den);
        owe_process(x1.y, t1.y, s_tab, acc_num, acc_den);
        owe_process(x1.z, t1.z, s_tab, acc_num, acc_den);
        owe_process(x1.w, t1.w, s_tab, acc_num, acc_den);
        owe_process(x2.x, t2.x, s_tab, acc_num, acc_den);
        owe_process(x2.y, t2.y, s_tab, acc_num, acc_den);
        owe_process(x2.z, t2.z, s_tab, acc_num, acc_den);
        owe_process(x2.w, t2.w, s_tab, acc_num, acc_den);
        owe_process(x3.x, t3.x, s_tab, acc_num, acc_den);
        owe_process(x3.y, t3.y, s_tab, acc_num, acc_den);
        owe_process(x3.z, t3.z, s_tab, acc_num, acc_den);
        owe_process(x3.w, t3.w, s_tab, acc_num, acc_den);
    } else {
        // tail block (only when n4 % (T*J) != 0)
        for (int j = 0; j < OWE_J; ++j) {
            int idx = base + j * OWE_T;
            if (idx < n4) {
                f32x4 x = __builtin_nontemporal_load(&in4[idx]);
                i32x4 t = __builtin_nontemporal_load(&tg4[idx]);
                owe_process(x.x, t.x, s_tab, acc_num, acc_den);
                owe_process(x.y, t.y, s_tab, acc_num, acc_den);
                owe_process(x.z, t.z, s_tab, acc_num, acc_den);
                owe_process(x.w, t.w, s_tab, acc_num, acc_den);
            }
        }
    }

    // wave64 reduction
    #pragma unroll
    for (int off = 32; off > 0; off >>= 1) {
        acc_num += __shfl_down(acc_num, off);
        acc_den += __shfl_down(acc_den, off);
    }
    int lane = threadIdx.x & 63;
    int wid  = threadIdx.x >> 6;
    if (lane == 0) s_part[wid] = make_float2(acc_num, acc_den);
    __syncthreads();
    if (threadIdx.x == 0) {
        float n = 0.0f, d = 0.0f;
        #pragma unroll
        for (int w = 0; w < OWE_T / 64; ++w) { n += s_part[w].x; d += s_part[w].y; }
        partials[blockIdx.x] = make_float2(n, d);
    }
}

__global__ __launch_bounds__(256) void owe_final_kernel(
    const float2* __restrict__ partials, int nparts,
    const float*  __restrict__ input, const int* __restrict__ target,
    const float*  __restrict__ weight, const float* __restrict__ dist,
    int n, float* __restrict__ out)
{
    __shared__ double s_n[4], s_d[4];
    double nn = 0.0, dd = 0.0;
    for (int i = threadIdx.x; i < nparts; i += 256) {
        float2 p = partials[i];
        nn += (double)p.x;
        dd += (double)p.y;
    }
    #pragma unroll
    for (int off = 32; off > 0; off >>= 1) {
        nn += __shfl_down(nn, off);
        dd += __shfl_down(dd, off);
    }
    int lane = threadIdx.x & 63;
    int wid  = threadIdx.x >> 6;
    if (lane == 0) { s_n[wid] = nn; s_d[wid] = dd; }
    __syncthreads();
    if (threadIdx.x == 0) {
        double N = 0.0, D = 0.0;
        #pragma unroll
        for (int w = 0; w < 4; ++w) { N += s_n[w]; D += s_d[w]; }
        // leftover elements (n % 4 != 0) — none for N=2^24, kept for generality
        int rem_start = (n / 4) * 4;
        if (rem_start < n) {
            float d0 = dist[0], d1 = dist[1], d2 = dist[2], d3 = dist[3], d4 = dist[4];
            float cs1 = d0 + d1, cs2 = cs1 + d2, cs3 = cs2 + d3, cs4 = cs3 + d4;
            float inv = 1.0f / (2.0f * cs4 - d0 - d4);
            float pcnl[5] = {(2.0f * d0  - d0 - d0) * inv, (2.0f * cs1 - d1 - d0) * inv,
                             (2.0f * cs2 - d2 - d0) * inv, (2.0f * cs3 - d3 - d0) * inv,
                             (2.0f * cs4 - d4 - d0) * inv};
            for (int i = rem_start; i < n; ++i) {
                float xv = input[i];
                int   tv = target[i];
                float f  = floorf(xv);
                float v0 = f, v1 = f + 1.0f;
                int c0 = min(max((int)v0, 0), 4), c1 = min(max((int)v1, 0), 4);
                float pf = (v0 >= 0.0f && v0 <= 4.0f) ? pcnl[c0] : v0 * 0.25f;
                float pc = (v1 >= 0.0f && v1 <= 4.0f) ? pcnl[c1] : v1 * 0.25f;
                float ip = pf + (pc - pf) * (xv - f);
                float diff = ip - pcnl[tv];
                float w = weight[tv];
                N += (double)(diff * diff * w);
                D += (double)w;
            }
        }
        out[0] = (float)(N / D);
    }
}

extern "C" void kernel_launch(void* const* d_in, const int* in_sizes, int n_in,
                              void* d_out, int out_size, void* d_ws, size_t ws_size,
                              hipStream_t stream) {
    const float* input  = (const float*)d_in[0];
    const int*   target = (const int*)  d_in[1];
    const float* weight = (const float*)d_in[2];
    const float* dist   = (const float*)d_in[3];
    float*  out      = (float*)d_out;
    float2* partials = (float2*)d_ws;

    int n  = in_sizes[0];
    int n4 = n / 4;
    int grid = (n4 + OWE_T * OWE_J - 1) / (OWE_T * OWE_J);   // 4096 for N=2^24

    owe_reduce_kernel<<<grid, OWE_T, 0, stream>>>(
        (const f32x4*)input, (const i32x4*)target, weight, dist, partials, n4);
    owe_final_kernel<<<1, 256, 0, stream>>>(
        partials, grid, input, target, weight, dist, n, out);
}